// Round 2
// baseline (234.153 us; speedup 1.0000x reference)
//
#include <hip/hip_runtime.h>
#include <stdint.h>

// ---------------- common helpers ----------------
typedef __attribute__((ext_vector_type(4))) float f32x4;
typedef __attribute__((ext_vector_type(8))) short bf16x8;

__device__ __forceinline__ unsigned short f2bf(float f) {
  union { float f; unsigned int u; } v; v.f = f;
  unsigned int r = v.u + 0x7fffu + ((v.u >> 16) & 1u);  // RNE
  return (unsigned short)(r >> 16);
}
__device__ __forceinline__ float bflo(unsigned int w) { return __uint_as_float(w << 16); }
__device__ __forceinline__ float bfhi(unsigned int w) { return __uint_as_float(w & 0xffff0000u); }
__device__ __forceinline__ unsigned int packbf2(float a, float b) {
  return (unsigned int)f2bf(a) | ((unsigned int)f2bf(b) << 16);
}

#define LDK 200  // LDS row pitch (bf16 elems): 192+8 -> 400B rows, 16B aligned, uniform bank spread
#define QSCALE 0.17677669529663689f  // 32^-0.5

// ---------------- kernel 1: qkv GEMM ----------------
// qkv[pixel][576] = x_nchw_transposed @ qkv_w^T + qkv_b  (bf16 out, q channels pre-scaled)
// One block per 64-pixel tile; A staged ONCE, loop over 9 N-tiles of qkv_w.
__global__ __launch_bounds__(256) void qkv_gemm(
    const float* __restrict__ x, const float* __restrict__ w,
    const float* __restrict__ bias, unsigned short* __restrict__ qkv) {
  __shared__ unsigned short Al[64 * LDK];
  __shared__ unsigned short Bl[64 * LDK];
  const int t = threadIdx.x;
  const int tm = blockIdx.x;        // 512 pixel tiles (64 px each; 4096%64==0 so no batch cross)
  const int bb = (tm * 64) >> 12, hw0 = (tm * 64) & 4095;
  const float* xb = x + (size_t)bb * 192 * 4096 + hw0;

  // stage A once: 64 pixels x 192 channels, transpose from NCHW (coalesced global reads)
  for (int j = 0; j < 12288; j += 256) {
    int idx = j + t;
    int m = idx & 63, c = idx >> 6;
    Al[m * LDK + c] = f2bf(xb[c * 4096 + m]);
  }

  const int lane = t & 63, wid = t >> 6;
  const int wm = (wid >> 1) * 32, wn = (wid & 1) * 32;  // 2x2 waves, 32x32 each
  const int lr = lane & 15, kb = (lane >> 4) * 8;
  const int r0 = (lane >> 4) * 4;
  unsigned short* opb = qkv + (size_t)(tm * 64) * 576;

  for (int n0 = 0; n0 < 576; n0 += 64) {
    if (n0) __syncthreads();  // protect Bl overwrite
    // stage B: qkv_w rows [n][k] (already B^T layout), fold q-scale
    for (int j = 0; j < 3072; j += 256) {
      int idx = j + t;
      int n = idx / 48, k = (idx % 48) * 4;
      int gn = n0 + n;
      float sc = ((gn % 192) < 64) ? QSCALE : 1.0f;
      const float4 wv = *(const float4*)(w + gn * 192 + k);
      ushort4 pk;
      pk.x = f2bf(wv.x * sc); pk.y = f2bf(wv.y * sc);
      pk.z = f2bf(wv.z * sc); pk.w = f2bf(wv.w * sc);
      *(ushort4*)&Bl[n * LDK + k] = pk;
    }
    __syncthreads();

    f32x4 acc[2][2];
    #pragma unroll
    for (int i = 0; i < 2; ++i)
      #pragma unroll
      for (int j = 0; j < 2; ++j)
        #pragma unroll
        for (int r = 0; r < 4; ++r) acc[i][j][r] = 0.0f;

    #pragma unroll
    for (int kk = 0; kk < 192; kk += 32) {
      bf16x8 a0 = *(const bf16x8*)&Al[(wm + lr) * LDK + kk + kb];
      bf16x8 a1 = *(const bf16x8*)&Al[(wm + 16 + lr) * LDK + kk + kb];
      bf16x8 b0 = *(const bf16x8*)&Bl[(wn + lr) * LDK + kk + kb];
      bf16x8 b1 = *(const bf16x8*)&Bl[(wn + 16 + lr) * LDK + kk + kb];
      acc[0][0] = __builtin_amdgcn_mfma_f32_16x16x32_bf16(a0, b0, acc[0][0], 0, 0, 0);
      acc[0][1] = __builtin_amdgcn_mfma_f32_16x16x32_bf16(a0, b1, acc[0][1], 0, 0, 0);
      acc[1][0] = __builtin_amdgcn_mfma_f32_16x16x32_bf16(a1, b0, acc[1][0], 0, 0, 0);
      acc[1][1] = __builtin_amdgcn_mfma_f32_16x16x32_bf16(a1, b1, acc[1][1], 0, 0, 0);
    }

    // D layout: col = lane&15, row = (lane>>4)*4 + reg  [m89-verified]
    #pragma unroll
    for (int i = 0; i < 2; ++i)
      #pragma unroll
      for (int j = 0; j < 2; ++j) {
        int col = wn + j * 16 + lr;
        int gn = n0 + col;
        float bs = bias[gn] * (((gn % 192) < 64) ? QSCALE : 1.0f);
        #pragma unroll
        for (int r = 0; r < 4; ++r) {
          int row = wm + i * 16 + r0 + r;
          opb[row * 576 + gn] = f2bf(acc[i][j][r] + bs);
        }
      }
  }
}

// ---------------- kernel 2: neighborhood attention (4 lanes per pixel) ----------------
template <int K, int DIL>
__device__ __forceinline__ void natten_branch(
    const unsigned short* __restrict__ qkv, const float* __restrict__ rpb,
    unsigned short* __restrict__ yo, const int branch, const int r) {
  constexpr int RW = 2 * K - 1;
  __shared__ float rs[RW * RW];
  const int t = threadIdx.x;
  const int bh = r & 15, tile = r >> 4;     // 64 tiles of 8x8 pixels
  const int head = bh & 1, bb = bh >> 1;
  for (int i = t; i < RW * RW; i += 256) rs[i] = rpb[head * RW * RW + i];
  __syncthreads();

  const int pix = t >> 2, sl = t & 3;       // 64 pixel slots x 4 lanes
  const int h = ((tile >> 3) << 3) + (pix >> 3);
  const int w = ((tile & 7) << 3) + (pix & 7);

  int gh = h % DIL, iih = h / DIL;
  int Lgh = (64 - gh + DIL - 1) / DIL;
  int s0h = iih - K / 2; if (s0h < 0) s0h = 0; if (s0h > Lgh - K) s0h = Lgh - K;
  int gw = w % DIL, iiw = w / DIL;
  int Lgw = (64 - gw + DIL - 1) / DIL;
  int s0w = iiw - K / 2; if (s0w < 0) s0w = 0; if (s0w > Lgw - K) s0w = Lgw - K;
  const int bhb = s0h - iih + (K - 1);      // bias base along h
  const int bwb = s0w - iiw + (K - 1);

  const int p = bb * 4096 + h * 64 + w;
  const unsigned short* qp = qkv + (size_t)p * 576 + branch * 192 + head * 32;
  float q[32];
  #pragma unroll
  for (int u = 0; u < 4; ++u) {
    uint4 v = *(const uint4*)(qp + u * 8);
    q[u*8+0] = bflo(v.x); q[u*8+1] = bfhi(v.x);
    q[u*8+2] = bflo(v.y); q[u*8+3] = bfhi(v.y);
    q[u*8+4] = bflo(v.z); q[u*8+5] = bfhi(v.z);
    q[u*8+6] = bflo(v.w); q[u*8+7] = bfhi(v.w);
  }
  float mx = -1e30f, l = 0.0f, acc[32];
  #pragma unroll
  for (int d = 0; d < 32; ++d) acc[d] = 0.0f;

  const unsigned short* kvb = qkv + (size_t)bb * 4096 * 576 + branch * 192 + 64 + head * 32;

  // each lane handles neighbors n = sl, sl+4, ... (own online-softmax state)
  for (int n = sl; n < K * K; n += 4) {
    const int kh = n / K, kw = n - kh * K;
    const int nh = gh + (s0h + kh) * DIL;
    const int nw = gw + (s0w + kw) * DIL;
    const unsigned short* kp = kvb + (size_t)(nh * 64 + nw) * 576;
    float s = rs[(bhb + kh) * RW + (bwb + kw)];
    #pragma unroll
    for (int u = 0; u < 4; ++u) {
      uint4 kv = *(const uint4*)(kp + u * 8);
      s += bflo(kv.x) * q[u*8+0] + bfhi(kv.x) * q[u*8+1]
         + bflo(kv.y) * q[u*8+2] + bfhi(kv.y) * q[u*8+3]
         + bflo(kv.z) * q[u*8+4] + bfhi(kv.z) * q[u*8+5]
         + bflo(kv.w) * q[u*8+6] + bfhi(kv.w) * q[u*8+7];
    }
    const float mn = fmaxf(mx, s);
    const float corr = __expf(mx - mn);
    const float pw = __expf(s - mn);
    mx = mn;
    l = l * corr + pw;
    #pragma unroll
    for (int u = 0; u < 4; ++u) {
      uint4 vv = *(const uint4*)(kp + 64 + u * 8);
      acc[u*8+0] = acc[u*8+0] * corr + pw * bflo(vv.x);
      acc[u*8+1] = acc[u*8+1] * corr + pw * bfhi(vv.x);
      acc[u*8+2] = acc[u*8+2] * corr + pw * bflo(vv.y);
      acc[u*8+3] = acc[u*8+3] * corr + pw * bfhi(vv.y);
      acc[u*8+4] = acc[u*8+4] * corr + pw * bflo(vv.z);
      acc[u*8+5] = acc[u*8+5] * corr + pw * bfhi(vv.z);
      acc[u*8+6] = acc[u*8+6] * corr + pw * bflo(vv.w);
      acc[u*8+7] = acc[u*8+7] * corr + pw * bfhi(vv.w);
    }
  }

  // merge the 4 per-lane softmax states (butterfly over lanes sl^1, sl^2)
  #pragma unroll
  for (int st = 1; st <= 2; st <<= 1) {
    float mo = __shfl_xor(mx, st, 64);
    float lo = __shfl_xor(l, st, 64);
    float mn = fmaxf(mx, mo);
    float c1 = __expf(mx - mn), c2 = __expf(mo - mn);
    mx = mn;
    l = l * c1 + lo * c2;
    #pragma unroll
    for (int d = 0; d < 32; ++d) {
      float ao = __shfl_xor(acc[d], st, 64);
      acc[d] = acc[d] * c1 + ao * c2;
    }
  }

  const float inv = 1.0f / l;
  // lane sl writes dim chunk [sl*8, sl*8+8): select with cndmask chains (no runtime indexing)
  float o[8];
  #pragma unroll
  for (int j = 0; j < 8; ++j) {
    float v01 = (sl == 0) ? acc[j] : acc[8 + j];
    float v23 = (sl == 2) ? acc[16 + j] : acc[24 + j];
    o[j] = (sl < 2) ? v01 : v23;
  }
  unsigned short* op = yo + (size_t)p * 192 + branch * 64 + head * 32 + sl * 8;
  uint4 pk;
  pk.x = packbf2(o[0] * inv, o[1] * inv);
  pk.y = packbf2(o[2] * inv, o[3] * inv);
  pk.z = packbf2(o[4] * inv, o[5] * inv);
  pk.w = packbf2(o[6] * inv, o[7] * inv);
  *(uint4*)op = pk;
}

__global__ __launch_bounds__(256) void natten_all(
    const unsigned short* __restrict__ qkv,
    const float* __restrict__ rpb0, const float* __restrict__ rpb1,
    const float* __restrict__ rpb2, unsigned short* __restrict__ yo) {
  const int gid = blockIdx.x;
  const int branch = gid % 3;  // interleave heavy/light branches across dispatch order
  const int r = gid / 3;
  if (branch == 0)      natten_branch<3, 1>(qkv, rpb0, yo, 0, r);
  else if (branch == 1) natten_branch<5, 2>(qkv, rpb1, yo, 1, r);
  else                  natten_branch<7, 3>(qkv, rpb2, yo, 2, r);
}

// ---------------- kernel 3: proj GEMM (computes C^T for coalesced NCHW stores) ----------------
// out[b][c][hw] = proj_w[c][:] . y[pixel][:] + proj_b[c]; y-tile staged once, loop c0.
__global__ __launch_bounds__(256) void proj_gemm(
    const unsigned short* __restrict__ y, const float* __restrict__ w,
    const float* __restrict__ bias, float* __restrict__ out) {
  __shared__ unsigned short Al[64 * LDK];  // A = proj_w rows (out channels x K)
  __shared__ unsigned short Bl[64 * LDK];  // B^T = y rows (pixels x K)
  const int t = threadIdx.x;
  const int tp = blockIdx.x;       // 512 pixel tiles

  const unsigned short* ybp = y + (size_t)(tp * 64) * 192;
  for (int j = 0; j < 1536; j += 256) {
    int idx = j + t;
    int m = idx / 24, k8 = (idx % 24) * 8;
    *(uint4*)&Bl[m * LDK + k8] = *(const uint4*)(ybp + m * 192 + k8);
  }

  const int lane = t & 63, wid = t >> 6;
  const int wm = (wid >> 1) * 32, wn = (wid & 1) * 32;
  const int lr = lane & 15, kb = (lane >> 4) * 8;
  const int r0 = (lane >> 4) * 4;
  const int gp = tp * 64;
  const int bb = gp >> 12, hw0 = gp & 4095;
  float* op = out + (size_t)bb * 192 * 4096 + hw0;

  for (int c0 = 0; c0 < 192; c0 += 64) {
    if (c0) __syncthreads();
    for (int j = 0; j < 3072; j += 256) {
      int idx = j + t;
      int n = idx / 48, k = (idx % 48) * 4;
      const float4 wv = *(const float4*)(w + (c0 + n) * 192 + k);
      ushort4 pk;
      pk.x = f2bf(wv.x); pk.y = f2bf(wv.y); pk.z = f2bf(wv.z); pk.w = f2bf(wv.w);
      *(ushort4*)&Al[n * LDK + k] = pk;
    }
    __syncthreads();

    f32x4 acc[2][2];
    #pragma unroll
    for (int i = 0; i < 2; ++i)
      #pragma unroll
      for (int j = 0; j < 2; ++j)
        #pragma unroll
        for (int r = 0; r < 4; ++r) acc[i][j][r] = 0.0f;

    #pragma unroll
    for (int kk = 0; kk < 192; kk += 32) {
      bf16x8 a0 = *(const bf16x8*)&Al[(wm + lr) * LDK + kk + kb];
      bf16x8 a1 = *(const bf16x8*)&Al[(wm + 16 + lr) * LDK + kk + kb];
      bf16x8 b0 = *(const bf16x8*)&Bl[(wn + lr) * LDK + kk + kb];
      bf16x8 b1 = *(const bf16x8*)&Bl[(wn + 16 + lr) * LDK + kk + kb];
      acc[0][0] = __builtin_amdgcn_mfma_f32_16x16x32_bf16(a0, b0, acc[0][0], 0, 0, 0);
      acc[0][1] = __builtin_amdgcn_mfma_f32_16x16x32_bf16(a0, b1, acc[0][1], 0, 0, 0);
      acc[1][0] = __builtin_amdgcn_mfma_f32_16x16x32_bf16(a1, b0, acc[1][0], 0, 0, 0);
      acc[1][1] = __builtin_amdgcn_mfma_f32_16x16x32_bf16(a1, b1, acc[1][1], 0, 0, 0);
    }

    #pragma unroll
    for (int i = 0; i < 2; ++i)
      #pragma unroll
      for (int j = 0; j < 2; ++j) {
        int m = wn + j * 16 + lr;  // pixel (D col)
        #pragma unroll
        for (int r = 0; r < 4; ++r) {
          int c = c0 + wm + i * 16 + r0 + r;  // out channel (D row)
          op[(size_t)c * 4096 + m] = acc[i][j][r] + bias[c];
        }
      }
  }
}

// ---------------- launch ----------------
extern "C" void kernel_launch(void* const* d_in, const int* in_sizes, int n_in,
                              void* d_out, int out_size, void* d_ws, size_t ws_size,
                              hipStream_t stream) {
  const float* x      = (const float*)d_in[0];
  const float* qkv_w  = (const float*)d_in[1];
  const float* qkv_b  = (const float*)d_in[2];
  const float* proj_w = (const float*)d_in[3];
  const float* proj_b = (const float*)d_in[4];
  const float* rpb0   = (const float*)d_in[5];
  const float* rpb1   = (const float*)d_in[6];
  const float* rpb2   = (const float*)d_in[7];

  unsigned short* qkv = (unsigned short*)d_ws;                        // 32768*576 bf16 = 37.75 MB
  unsigned short* yb  = (unsigned short*)d_ws + (size_t)32768 * 576;  // 32768*192 bf16 = 12.58 MB
  float* out = (float*)d_out;

  qkv_gemm<<<dim3(512), 256, 0, stream>>>(x, qkv_w, qkv_b, qkv);
  natten_all<<<dim3(3072), 256, 0, stream>>>(qkv, rpb0, rpb1, rpb2, yb);
  proj_gemm<<<dim3(512), 256, 0, stream>>>(yb, proj_w, proj_b, out);
}

// Round 3
// 158.052 us; speedup vs baseline: 1.4815x; 1.4815x over previous
//
#include <hip/hip_runtime.h>
#include <stdint.h>

// ---------------- common types/helpers ----------------
typedef __attribute__((ext_vector_type(4))) float f32x4;
typedef _Float16 half8 __attribute__((ext_vector_type(8)));
typedef _Float16 half2v __attribute__((ext_vector_type(2)));

#define LDK 200  // LDS row pitch (halves): 192+8, rows 400B (16B-aligned)
#define QSCALE 0.17677669529663689f  // 32^-0.5

__device__ __forceinline__ float dot2f(unsigned int k2, unsigned int q2, float c) {
#if __has_builtin(__builtin_amdgcn_fdot2)
  return __builtin_amdgcn_fdot2(__builtin_bit_cast(half2v, k2),
                                __builtin_bit_cast(half2v, q2), c, false);
#else
  half2v a = __builtin_bit_cast(half2v, k2), b = __builtin_bit_cast(half2v, q2);
  return c + (float)a.x * (float)b.x + (float)a.y * (float)b.y;
#endif
}

// ---------------- kernel 0: prep (qkv_w -> f16 with q-scale folded; scaled bias) ----------------
__global__ __launch_bounds__(256) void prep_w(
    const float* __restrict__ qw, const float* __restrict__ qb,
    _Float16* __restrict__ qwh, float* __restrict__ qbs) {
  int i = blockIdx.x * 256 + threadIdx.x;
  if (i < 27648) {  // 110592/4 float4s; 48 float4 per row (no straddle)
    float4 v = ((const float4*)qw)[i];
    int n = (i * 4) / 192;
    float sc = ((n % 192) < 64) ? QSCALE : 1.0f;
    _Float16* d = qwh + i * 4;
    d[0] = (_Float16)(v.x * sc); d[1] = (_Float16)(v.y * sc);
    d[2] = (_Float16)(v.z * sc); d[3] = (_Float16)(v.w * sc);
  } else if (i < 27648 + 576) {
    int n = i - 27648;
    qbs[n] = qb[n] * (((n % 192) < 64) ? QSCALE : 1.0f);
  }
}

// ---------------- kernel 1: qkv GEMM ----------------
// qkv[pixel][576] = x^T @ qkv_w^T + b (f16 out, q pre-scaled). A staged once; B direct from global.
__global__ __launch_bounds__(256) void qkv_gemm(
    const float* __restrict__ x, const _Float16* __restrict__ wh,
    const float* __restrict__ qbs, _Float16* __restrict__ qkv) {
  __shared__ _Float16 Al[64 * LDK];
  const int t = threadIdx.x;
  const int tm = blockIdx.x;  // 512 pixel tiles
  const int bb = (tm * 64) >> 12, hw0 = (tm * 64) & 4095;
  const float* xb = x + (size_t)bb * 192 * 4096 + hw0;

  // stage A: 64 px x 192 ch, transpose from NCHW; float4 loads (coalesced)
  #pragma unroll
  for (int j = 0; j < 12; ++j) {
    int idx = j * 256 + t;
    int m4 = (idx & 15) * 4, c = idx >> 4;
    float4 v = *(const float4*)(xb + (size_t)c * 4096 + m4);
    Al[(m4 + 0) * LDK + c] = (_Float16)v.x;
    Al[(m4 + 1) * LDK + c] = (_Float16)v.y;
    Al[(m4 + 2) * LDK + c] = (_Float16)v.z;
    Al[(m4 + 3) * LDK + c] = (_Float16)v.w;
  }
  __syncthreads();

  const int lane = t & 63, wid = t >> 6;
  const int wm = (wid >> 1) * 32, wn = (wid & 1) * 32;  // 2x2 waves, 32x32 each
  const int lr = lane & 15, kb = (lane >> 4) * 8;
  const int r0 = (lane >> 4) * 4;
  _Float16* opb = qkv + (size_t)(tm * 64) * 576;

  for (int n0 = 0; n0 < 576; n0 += 64) {
    f32x4 acc[2][2];
    #pragma unroll
    for (int i = 0; i < 2; ++i)
      #pragma unroll
      for (int j = 0; j < 2; ++j)
        #pragma unroll
        for (int r = 0; r < 4; ++r) acc[i][j][r] = 0.0f;

    #pragma unroll
    for (int kk = 0; kk < 192; kk += 32) {
      half8 a0 = *(const half8*)&Al[(wm + lr) * LDK + kk + kb];
      half8 a1 = *(const half8*)&Al[(wm + 16 + lr) * LDK + kk + kb];
      half8 b0 = *(const half8*)(wh + (size_t)(n0 + wn + lr) * 192 + kk + kb);
      half8 b1 = *(const half8*)(wh + (size_t)(n0 + wn + 16 + lr) * 192 + kk + kb);
      acc[0][0] = __builtin_amdgcn_mfma_f32_16x16x32_f16(a0, b0, acc[0][0], 0, 0, 0);
      acc[0][1] = __builtin_amdgcn_mfma_f32_16x16x32_f16(a0, b1, acc[0][1], 0, 0, 0);
      acc[1][0] = __builtin_amdgcn_mfma_f32_16x16x32_f16(a1, b0, acc[1][0], 0, 0, 0);
      acc[1][1] = __builtin_amdgcn_mfma_f32_16x16x32_f16(a1, b1, acc[1][1], 0, 0, 0);
    }

    // D: col = lane&15, row = (lane>>4)*4 + reg
    #pragma unroll
    for (int i = 0; i < 2; ++i)
      #pragma unroll
      for (int j = 0; j < 2; ++j) {
        int gn = n0 + wn + j * 16 + lr;
        float bs = qbs[gn];
        #pragma unroll
        for (int r = 0; r < 4; ++r) {
          int row = wm + i * 16 + r0 + r;
          opb[row * 576 + gn] = (_Float16)(acc[i][j][r] + bs);
        }
      }
  }
}

// ---------------- kernel 2: neighborhood attention (class-tiled, LDS halo) ----------------
template <int K, int DIL>
__device__ __forceinline__ void natten_branch(
    const _Float16* __restrict__ qkv, const float* __restrict__ rpb,
    _Float16* __restrict__ yo, const int branch, const int r,
    unsigned short* __restrict__ smem) {
  constexpr int RW = 2 * K - 1;
  constexpr int H8 = K + 7;        // halo span = 8 + K - 1
  constexpr int NH = H8 * H8;
  constexpr int NL = (K * K + 3) / 4;
  constexpr int LSTR = 40;         // halves per halo row (32 + 8 pad), 80B

  _Float16* Kl = (_Float16*)smem;
  _Float16* Vl = Kl + NH * LSTR;
  _Float16* Ql = Vl + NH * LSTR;
  float* rs = (float*)(Ql + 64 * LSTR);

  const int t = threadIdx.x;
  const int bh = r & 15;
  const int head = bh & 1, bb = bh >> 1;
  const int rr = r >> 4;
  int gh, gw, ti, tj, Lgh, Lgw;
  if (DIL == 1) {
    gh = 0; gw = 0; ti = (rr >> 3) * 8; tj = (rr & 7) * 8; Lgh = 64; Lgw = 64;
  } else if (DIL == 2) {
    int cls = rr >> 4, tile = rr & 15;
    gh = cls >> 1; gw = cls & 1; ti = (tile >> 2) * 8; tj = (tile & 3) * 8;
    Lgh = 32; Lgw = 32;
  } else {
    int cls = rr / 9, tile = rr % 9;
    gh = cls / 3; gw = cls % 3; ti = (tile / 3) * 8; tj = (tile % 3) * 8;
    Lgh = (64 - gh + 2) / 3; Lgw = (64 - gw + 2) / 3;
  }
  const int hoh = max(0, min(ti - K / 2, Lgh - K));
  const int how = max(0, min(tj - K / 2, Lgw - K));

  for (int i = t; i < RW * RW; i += 256) rs[i] = rpb[head * RW * RW + i];

  // stage halo K/V (each 16B chunk by one thread)
  const _Float16* kvb = qkv + (size_t)bb * 4096 * 576 + branch * 192 + 64 + head * 32;
  for (int L = t; L < NH * 8; L += 256) {
    int px = L >> 3, part = L & 7;
    int hr = px / H8, hc = px % H8;
    int cr = min(hoh + hr, Lgh - 1), cc = min(how + hc, Lgw - 1);
    int ph = gh + cr * DIL, pw2 = gw + cc * DIL;
    const _Float16* src = kvb + (size_t)(ph * 64 + pw2) * 576 + (part & 3) * 8 + ((part & 4) ? 64 : 0);
    _Float16* dst = ((part & 4) ? Vl : Kl) + px * LSTR + (part & 3) * 8;
    *(uint4*)dst = *(const uint4*)src;
  }
  // stage Q for 64 tile queries (clamped for ragged edges)
  {
    int qi = t >> 2, part = t & 3;
    int ci0 = min(ti + (qi >> 3), Lgh - 1), cj0 = min(tj + (qi & 7), Lgw - 1);
    int ph = gh + ci0 * DIL, pw2 = gw + cj0 * DIL;
    const _Float16* src = qkv + (size_t)((size_t)bb * 4096 + ph * 64 + pw2) * 576
                          + branch * 192 + head * 32 + part * 8;
    *(uint4*)(Ql + qi * LSTR + part * 8) = *(const uint4*)src;
  }
  __syncthreads();

  const int qi = t >> 2, sl = t & 3;
  const int ci = ti + (qi >> 3), cj = tj + (qi & 7);
  const bool valid = (ci < Lgh) && (cj < Lgw);

  int s0h = ci - K / 2; if (s0h < 0) s0h = 0; if (s0h > Lgh - K) s0h = Lgh - K;
  int s0w = cj - K / 2; if (s0w < 0) s0w = 0; if (s0w > Lgw - K) s0w = Lgw - K;
  const int rbase = s0h - hoh, cbase = s0w - how;          // in [0,7]
  const int bhb = s0h - ci + K - 1, bwb = s0w - cj + K - 1;

  // q packed pairs from LDS (broadcast within 4-lane group)
  unsigned int qh[16];
  #pragma unroll
  for (int u = 0; u < 4; ++u) {
    uint4 v = *(const uint4*)(Ql + qi * LSTR + u * 8);
    qh[u * 4 + 0] = v.x; qh[u * 4 + 1] = v.y; qh[u * 4 + 2] = v.z; qh[u * 4 + 3] = v.w;
  }

  // pass 1: scores for this lane's neighbors (n = sl + 4j)
  float s[NL];
  float mx = -1e30f;
  #pragma unroll
  for (int j = 0; j < NL; ++j) {
    int n = sl + 4 * j;
    if (n < K * K) {
      int kh = n / K, kw = n % K;
      int lidx = (rbase + kh) * H8 + (cbase + kw);
      const _Float16* kp = Kl + lidx * LSTR;
      float sc = rs[(bhb + kh) * RW + (bwb + kw)];
      #pragma unroll
      for (int u = 0; u < 4; ++u) {
        uint4 kv = *(const uint4*)(kp + u * 8);
        sc = dot2f(kv.x, qh[4 * u + 0], sc);
        sc = dot2f(kv.y, qh[4 * u + 1], sc);
        sc = dot2f(kv.z, qh[4 * u + 2], sc);
        sc = dot2f(kv.w, qh[4 * u + 3], sc);
      }
      s[j] = sc;
      mx = fmaxf(mx, sc);
    } else {
      s[j] = -1e30f;
    }
  }
  // merge max over the 4 lanes of this query
  mx = fmaxf(mx, __shfl_xor(mx, 1, 64));
  mx = fmaxf(mx, __shfl_xor(mx, 2, 64));

  float pw[NL];
  float l = 0.0f;
  #pragma unroll
  for (int j = 0; j < NL; ++j) { pw[j] = __expf(s[j] - mx); l += pw[j]; }
  l += __shfl_xor(l, 1, 64);
  l += __shfl_xor(l, 2, 64);

  // pass 2: PV with packed f16 accumulation
  half2v acch[16];
  #pragma unroll
  for (int i = 0; i < 16; ++i) acch[i] = (half2v)(_Float16)0.0f;
  #pragma unroll
  for (int j = 0; j < NL; ++j) {
    int n = sl + 4 * j;
    if (n < K * K) {
      int kh = n / K, kw = n % K;
      int lidx = (rbase + kh) * H8 + (cbase + kw);
      const _Float16* vp = Vl + lidx * LSTR;
      _Float16 ph = (_Float16)pw[j];
      half2v pp = {ph, ph};
      #pragma unroll
      for (int u = 0; u < 4; ++u) {
        uint4 vv = *(const uint4*)(vp + u * 8);
        acch[4 * u + 0] += pp * __builtin_bit_cast(half2v, vv.x);
        acch[4 * u + 1] += pp * __builtin_bit_cast(half2v, vv.y);
        acch[4 * u + 2] += pp * __builtin_bit_cast(half2v, vv.z);
        acch[4 * u + 3] += pp * __builtin_bit_cast(half2v, vv.w);
      }
    }
  }
  // butterfly-sum accumulators over the 4 lanes
  #pragma unroll
  for (int st = 1; st <= 2; st <<= 1) {
    #pragma unroll
    for (int i = 0; i < 16; ++i) {
      unsigned int o = __shfl_xor(__builtin_bit_cast(unsigned int, acch[i]), st, 64);
      acch[i] += __builtin_bit_cast(half2v, o);
    }
  }

  if (valid) {
    float inv = 1.0f / l;
    _Float16 ih = (_Float16)inv;
    half2v iv = {ih, ih};
    // lane sl writes dims [8sl, 8sl+8) = pair-regs acch[4sl .. 4sl+3]
    unsigned int a[16];
    #pragma unroll
    for (int i = 0; i < 16; ++i) a[i] = __builtin_bit_cast(unsigned int, acch[i]);
    uint4 pk;
    unsigned int r0, r1, r2, r3;
    r0 = (sl < 2) ? ((sl == 0) ? a[0] : a[4]) : ((sl == 2) ? a[8] : a[12]);
    r1 = (sl < 2) ? ((sl == 0) ? a[1] : a[5]) : ((sl == 2) ? a[9] : a[13]);
    r2 = (sl < 2) ? ((sl == 0) ? a[2] : a[6]) : ((sl == 2) ? a[10] : a[14]);
    r3 = (sl < 2) ? ((sl == 0) ? a[3] : a[7]) : ((sl == 2) ? a[11] : a[15]);
    pk.x = __builtin_bit_cast(unsigned int, __builtin_bit_cast(half2v, r0) * iv);
    pk.y = __builtin_bit_cast(unsigned int, __builtin_bit_cast(half2v, r1) * iv);
    pk.z = __builtin_bit_cast(unsigned int, __builtin_bit_cast(half2v, r2) * iv);
    pk.w = __builtin_bit_cast(unsigned int, __builtin_bit_cast(half2v, r3) * iv);
    const int p = bb * 4096 + (gh + ci * DIL) * 64 + (gw + cj * DIL);
    *(uint4*)(yo + (size_t)p * 192 + branch * 64 + head * 32 + sl * 8) = pk;
  }
}

__global__ __launch_bounds__(256) void natten_all(
    const _Float16* __restrict__ qkv,
    const float* __restrict__ rpb0, const float* __restrict__ rpb1,
    const float* __restrict__ rpb2, _Float16* __restrict__ yo) {
  __shared__ __align__(16) unsigned short smem[18624];  // max: K=7 -> 37.2 KB
  const int gid = blockIdx.x;
  if (gid < 1296)       natten_branch<7, 3>(qkv, rpb2, yo, 2, gid, smem);
  else if (gid < 2320)  natten_branch<5, 2>(qkv, rpb1, yo, 1, gid - 1296, smem);
  else                  natten_branch<3, 1>(qkv, rpb0, yo, 0, gid - 2320, smem);
}

// ---------------- kernel 3: proj GEMM (C^T for coalesced NCHW f32 stores) ----------------
__global__ __launch_bounds__(256) void proj_gemm(
    const _Float16* __restrict__ y, const float* __restrict__ w,
    const float* __restrict__ bias, float* __restrict__ out) {
  __shared__ _Float16 Al[64 * LDK];  // proj_w tile (out-ch x K), converted f32->f16
  __shared__ _Float16 Bl[64 * LDK];  // y tile (pixels x K)
  const int t = threadIdx.x;
  const int tp = blockIdx.x;  // 512 pixel tiles

  const _Float16* ybp = y + (size_t)(tp * 64) * 192;
  #pragma unroll
  for (int j = 0; j < 6; ++j) {
    int idx = j * 256 + t;
    int m = idx / 24, k8 = (idx % 24) * 8;
    *(uint4*)&Bl[m * LDK + k8] = *(const uint4*)(ybp + m * 192 + k8);
  }

  const int lane = t & 63, wid = t >> 6;
  const int wm = (wid >> 1) * 32, wn = (wid & 1) * 32;
  const int lr = lane & 15, kb = (lane >> 4) * 8;
  const int r0 = (lane >> 4) * 4;
  const int gp = tp * 64;
  const int bb = gp >> 12, hw0 = gp & 4095;
  float* op = out + (size_t)bb * 192 * 4096 + hw0;

  for (int c0 = 0; c0 < 192; c0 += 64) {
    if (c0) __syncthreads();
    #pragma unroll
    for (int j = 0; j < 12; ++j) {
      int idx = j * 256 + t;
      int n = idx / 48, k = (idx % 48) * 4;
      const float4 wv = *(const float4*)(w + (size_t)(c0 + n) * 192 + k);
      Al[n * LDK + k + 0] = (_Float16)wv.x;
      Al[n * LDK + k + 1] = (_Float16)wv.y;
      Al[n * LDK + k + 2] = (_Float16)wv.z;
      Al[n * LDK + k + 3] = (_Float16)wv.w;
    }
    __syncthreads();

    f32x4 acc[2][2];
    #pragma unroll
    for (int i = 0; i < 2; ++i)
      #pragma unroll
      for (int j = 0; j < 2; ++j)
        #pragma unroll
        for (int r = 0; r < 4; ++r) acc[i][j][r] = 0.0f;

    #pragma unroll
    for (int kk = 0; kk < 192; kk += 32) {
      half8 a0 = *(const half8*)&Al[(wm + lr) * LDK + kk + kb];
      half8 a1 = *(const half8*)&Al[(wm + 16 + lr) * LDK + kk + kb];
      half8 b0 = *(const half8*)&Bl[(wn + lr) * LDK + kk + kb];
      half8 b1 = *(const half8*)&Bl[(wn + 16 + lr) * LDK + kk + kb];
      acc[0][0] = __builtin_amdgcn_mfma_f32_16x16x32_f16(a0, b0, acc[0][0], 0, 0, 0);
      acc[0][1] = __builtin_amdgcn_mfma_f32_16x16x32_f16(a0, b1, acc[0][1], 0, 0, 0);
      acc[1][0] = __builtin_amdgcn_mfma_f32_16x16x32_f16(a1, b0, acc[1][0], 0, 0, 0);
      acc[1][1] = __builtin_amdgcn_mfma_f32_16x16x32_f16(a1, b1, acc[1][1], 0, 0, 0);
    }

    #pragma unroll
    for (int i = 0; i < 2; ++i)
      #pragma unroll
      for (int j = 0; j < 2; ++j) {
        int m = wn + j * 16 + lr;  // pixel (D col)
        #pragma unroll
        for (int r = 0; r < 4; ++r) {
          int c = c0 + wm + i * 16 + r0 + r;  // out channel (D row)
          op[(size_t)c * 4096 + m] = acc[i][j][r] + bias[c];
        }
      }
  }
}

// ---------------- launch ----------------
extern "C" void kernel_launch(void* const* d_in, const int* in_sizes, int n_in,
                              void* d_out, int out_size, void* d_ws, size_t ws_size,
                              hipStream_t stream) {
  const float* x      = (const float*)d_in[0];
  const float* qkv_w  = (const float*)d_in[1];
  const float* qkv_b  = (const float*)d_in[2];
  const float* proj_w = (const float*)d_in[3];
  const float* proj_b = (const float*)d_in[4];
  const float* rpb0   = (const float*)d_in[5];
  const float* rpb1   = (const float*)d_in[6];
  const float* rpb2   = (const float*)d_in[7];

  // ws: qkv f16 (32768*576), yb f16 (32768*192) -> 50.33 MB (same footprint as prior rounds)
  _Float16* qkv = (_Float16*)d_ws;
  _Float16* yb  = (_Float16*)d_ws + (size_t)32768 * 576;
  // d_out head used as scratch for prepped qkv_w/bias (proj_gemm later overwrites all of d_out)
  _Float16* qwh = (_Float16*)d_out;                       // 110592 halves = 221184 B
  float*    qbs = (float*)((char*)d_out + 221184);        // 576 f32
  float* out = (float*)d_out;

  prep_w<<<dim3(111), 256, 0, stream>>>(qkv_w, qkv_b, qwh, qbs);
  qkv_gemm<<<dim3(512), 256, 0, stream>>>(x, qwh, qbs, qkv);
  natten_all<<<dim3(3344), 256, 0, stream>>>(qkv, rpb0, rpb1, rpb2, yb);
  proj_gemm<<<dim3(512), 256, 0, stream>>>(yb, proj_w, proj_b, out);
}